// Round 1
// baseline (347.891 us; speedup 1.0000x reference)
//
#include <hip/hip_runtime.h>
#include <hip/hip_bf16.h>
#include <stdint.h>

// B=4, T=2048, INPUT_DIM=1024, DIM=64, H=16
typedef __attribute__((ext_vector_type(8))) short bf16x8;
typedef __attribute__((ext_vector_type(4))) float f32x4;

__device__ __forceinline__ void mfma_bf16(f32x4& c, bf16x8 a, bf16x8 b) {
  // D = A*B + C, C/D in VGPRs (gfx950 unified file)
  asm("v_mfma_f32_16x16x32_bf16 %0, %1, %2, %0" : "+v"(c) : "v"(a), "v"(b));
}

__device__ __forceinline__ void gload_lds16(const void* g, void* lds) {
  __builtin_amdgcn_global_load_lds(
      (const __attribute__((address_space(1))) void*)g,
      (__attribute__((address_space(3))) void*)lds, 16, 0, 0);
}

// ---------------- f32 -> bf16 convert (vectorized) ----------------
__global__ void cvt_f32_bf16(const float* __restrict__ in, __hip_bfloat16* __restrict__ out, int n4) {
  int i = blockIdx.x * blockDim.x + threadIdx.x;
  if (i >= n4) return;
  float4 v = reinterpret_cast<const float4*>(in)[i];
  __hip_bfloat162 a = __float22bfloat162_rn(make_float2(v.x, v.y));
  __hip_bfloat162 b = __float22bfloat162_rn(make_float2(v.z, v.w));
  reinterpret_cast<__hip_bfloat162*>(out)[i * 2]     = a;
  reinterpret_cast<__hip_bfloat162*>(out)[i * 2 + 1] = b;
}

// ------------- transpose [R][C] f32 -> [C][R] bf16 -------------
__global__ void transpose_cvt(const float* __restrict__ in, __hip_bfloat16* __restrict__ out,
                              int R, int C) {
  __shared__ float tile[32][33];
  int c0 = blockIdx.x * 32, r0 = blockIdx.y * 32;
#pragma unroll
  for (int k = 0; k < 4; k++)
    tile[threadIdx.y + 8 * k][threadIdx.x] =
        in[(size_t)(r0 + threadIdx.y + 8 * k) * C + c0 + threadIdx.x];
  __syncthreads();
#pragma unroll
  for (int k = 0; k < 4; k++)
    out[(size_t)(c0 + threadIdx.y + 8 * k) * R + r0 + threadIdx.x] =
        __float2bfloat16(tile[threadIdx.x][threadIdx.y + 8 * k]);
}

// ---------------- bf16 GEMM, m97 structure: 128x128 tile, BK=32 ----------------
// A: [M][K] row-major bf16 ; Bt: [N][K] row-major bf16 (i.e. B transposed)
// MODE 0: scatter into q/k/v [B,H,T,64] (q scaled by 0.125) ; MODE 1: f32 out + bias
template <int MODE>
__global__ __launch_bounds__(256) void gemm_bf16(
    const __hip_bfloat16* __restrict__ A, const __hip_bfloat16* __restrict__ Bt,
    int M, int N, int K,
    __hip_bfloat16* __restrict__ qb, __hip_bfloat16* __restrict__ kb,
    __hip_bfloat16* __restrict__ vb,
    float* __restrict__ outp, const float* __restrict__ bias) {
  constexpr int BK = 32;
  __shared__ __align__(16) __hip_bfloat16 As[128 * BK];
  __shared__ __align__(16) __hip_bfloat16 Bs[128 * BK];
  const int tid = threadIdx.x;
  const int wave = tid >> 6, lane = tid & 63;
  const int wr = wave >> 1, wc = wave & 1;
  const int m0 = blockIdx.y * 128, n0 = blockIdx.x * 128;

  f32x4 acc[4][4];
#pragma unroll
  for (int i = 0; i < 4; i++)
#pragma unroll
    for (int j = 0; j < 4; j++) acc[i][j] = (f32x4)(0.0f);

  // staging: 8 chunks of 1KB (16 rows x 64B); wave w owns chunks 2w, 2w+1
  const int c0 = wave * 2, c1 = c0 + 1;
  const int srow0 = c0 * 16 + (lane >> 2);
  const int srow1 = c1 * 16 + (lane >> 2);
  const int scol = (lane & 3) * 8;  // elements
  const __hip_bfloat16* Ag0 = A + (size_t)(m0 + srow0) * K + scol;
  const __hip_bfloat16* Ag1 = A + (size_t)(m0 + srow1) * K + scol;
  const __hip_bfloat16* Bg0 = Bt + (size_t)(n0 + srow0) * K + scol;
  const __hip_bfloat16* Bg1 = Bt + (size_t)(n0 + srow1) * K + scol;
  __hip_bfloat16* AsP0 = &As[c0 * 512];
  __hip_bfloat16* AsP1 = &As[c1 * 512];
  __hip_bfloat16* BsP0 = &Bs[c0 * 512];
  __hip_bfloat16* BsP1 = &Bs[c1 * 512];

  for (int kk = 0; kk < K; kk += BK) {
    gload_lds16(Ag0 + kk, AsP0);
    gload_lds16(Ag1 + kk, AsP1);
    gload_lds16(Bg0 + kk, BsP0);
    gload_lds16(Bg1 + kk, BsP1);
    __syncthreads();  // compiler drains vmcnt before barrier
    bf16x8 af[4], bfr[4];
#pragma unroll
    for (int i = 0; i < 4; i++)
      af[i] = *(const bf16x8*)&As[(wr * 64 + i * 16 + (lane & 15)) * BK + (lane >> 4) * 8];
#pragma unroll
    for (int j = 0; j < 4; j++)
      bfr[j] = *(const bf16x8*)&Bs[(wc * 64 + j * 16 + (lane & 15)) * BK + (lane >> 4) * 8];
#pragma unroll
    for (int i = 0; i < 4; i++)
#pragma unroll
      for (int j = 0; j < 4; j++) mfma_bf16(acc[i][j], af[i], bfr[j]);
    __syncthreads();
  }

  if constexpr (MODE == 0) {
#pragma unroll
    for (int j = 0; j < 4; j++) {
      int col = n0 + wc * 64 + j * 16 + (lane & 15);  // col = sel*1024 + h*64 + d
      int sel = col >> 10;
      int h = (col >> 6) & 15;
      int d = col & 63;
      __hip_bfloat16* dst = (sel == 0) ? qb : ((sel == 1) ? kb : vb);
      float scl = (sel == 0) ? 0.125f : 1.0f;  // fold 1/sqrt(64) into Q (exact in bf16)
#pragma unroll
      for (int i = 0; i < 4; i++) {
#pragma unroll
        for (int r = 0; r < 4; r++) {
          int row = m0 + wr * 64 + i * 16 + (lane >> 4) * 4 + r;  // row = b*2048 + t
          int b = row >> 11, t = row & 2047;
          dst[(((size_t)b * 16 + h) * 2048 + t) * 64 + d] = __float2bfloat16(acc[i][j][r] * scl);
        }
      }
    }
  } else {
#pragma unroll
    for (int j = 0; j < 4; j++) {
      int col = n0 + wc * 64 + j * 16 + (lane & 15);
      float bv = bias[col];
#pragma unroll
      for (int i = 0; i < 4; i++) {
#pragma unroll
        for (int r = 0; r < 4; r++) {
          int row = m0 + wr * 64 + i * 16 + (lane >> 4) * 4 + r;
          outp[(size_t)row * N + col] = acc[i][j][r] + bv;
        }
      }
    }
  }
}

// ---------------- flash attention ----------------
// Q,K,V: [B*H][T][64] bf16 (Q pre-scaled). Out: [B*T][1024] bf16.
// Block: 256 thr = 4 waves; 64 q-rows/block (16/wave); KV tiles of 64.
// Swapped QK^T: S^T = K·Q^T so each lane owns one q-row (lane&15) -> in-reg softmax.
__global__ __launch_bounds__(256) void attn_fwd(
    const __hip_bfloat16* __restrict__ Qb, const __hip_bfloat16* __restrict__ Kb,
    const __hip_bfloat16* __restrict__ Vb, __hip_bfloat16* __restrict__ Ob) {
  constexpr int T = 2048;
  __shared__ __align__(16) __hip_bfloat16 Ks[64 * 64];      // [key][d], swizzled
  __shared__ __align__(16) __hip_bfloat16 Vt[64 * 64];      // [d][key], swizzled
  __shared__ __align__(16) __hip_bfloat16 Ps[4][16 * 64];   // per-wave P[qrow][key], swizzled
  const int tid = threadIdx.x, wave = tid >> 6, lane = tid & 63;
  const int bh = blockIdx.y, q0 = blockIdx.x * 64;
  const size_t base = (size_t)bh * T * 64;

  bf16x8 qf[2];
  {
    const int qrow = q0 + wave * 16 + (lane & 15);
#pragma unroll
    for (int ks = 0; ks < 2; ks++)
      qf[ks] = *(const bf16x8*)&Qb[base + (size_t)qrow * 64 + ks * 32 + (lane >> 4) * 8];
  }

  float m_run = -3.0e38f, l_run = 0.0f;  // for q-row = lane&15
  f32x4 o[4];
#pragma unroll
  for (int fd = 0; fd < 4; fd++) o[fd] = (f32x4)(0.0f);

  const int sr = lane >> 3;                        // row-in-chunk 0..7
  const int scb = ((lane & 7) * 16) ^ (sr << 4);   // pre-swizzled source col-byte (rule #21)
  const char* KgB = (const char*)(Kb + base);
  char* KsB = (char*)Ks;
  char* VtB = (char*)Vt;
  char* PwB = (char*)&Ps[wave][0];

  for (int kt = 0; kt < T / 64; kt++) {
    {  // stage K: global_load_lds, linear LDS dest + swizzled global source
      const int cc0 = wave * 2, cc1 = cc0 + 1;
      gload_lds16(KgB + (size_t)(kt * 64 + cc0 * 8 + sr) * 128 + scb, KsB + cc0 * 1024);
      gload_lds16(KgB + (size_t)(kt * 64 + cc1 * 8 + sr) * 128 + scb, KsB + cc1 * 1024);
    }
    {  // stage V transposed via regs: Vt[d][key] = V[key][d]
      const __hip_bfloat16* Vg = Vb + base + (size_t)kt * 64 * 64;
#pragma unroll
      for (int it = 0; it < 2; it++) {
        int idx = it * 256 + tid;
        int key = idx >> 3, j8 = idx & 7;
        bf16x8 vv = *(const bf16x8*)&Vg[key * 64 + j8 * 8];
#pragma unroll
        for (int j = 0; j < 8; j++) {
          int d = j8 * 8 + j;
          int byteoff = (d * 128 + key * 2) ^ ((d & 7) << 4);
          *(short*)(VtB + byteoff) = (short)vv[j];
        }
      }
    }
    __syncthreads();

    // S^T = K · Q^T : lane owns (key = kf*16 + (lane>>4)*4 + reg, qrow = lane&15)
    f32x4 s[4];
#pragma unroll
    for (int kf = 0; kf < 4; kf++) s[kf] = (f32x4)(0.0f);
#pragma unroll
    for (int ks = 0; ks < 2; ks++) {
#pragma unroll
      for (int kf = 0; kf < 4; kf++) {
        int key = kf * 16 + (lane & 15);
        int byteoff = (key * 128 + ks * 64 + (lane >> 4) * 16) ^ ((key & 7) << 4);
        bf16x8 kfrag = *(const bf16x8*)(KsB + byteoff);
        mfma_bf16(s[kf], kfrag, qf[ks]);
      }
    }

    // online softmax, row-local in lane (reduce 16 in-reg + 2 shfl across key groups)
    float tm = s[0][0];
#pragma unroll
    for (int kf = 0; kf < 4; kf++)
#pragma unroll
      for (int r = 0; r < 4; r++) tm = fmaxf(tm, s[kf][r]);
    tm = fmaxf(tm, __shfl_xor(tm, 16));
    tm = fmaxf(tm, __shfl_xor(tm, 32));
    float mn = fmaxf(m_run, tm);
    float alpha = __expf(m_run - mn);
    m_run = mn;
    float p[4][4];
    float rs = 0.0f;
#pragma unroll
    for (int kf = 0; kf < 4; kf++)
#pragma unroll
      for (int r = 0; r < 4; r++) {
        float pv = __expf(s[kf][r] - mn);
        p[kf][r] = pv;
        rs += pv;
      }
    rs += __shfl_xor(rs, 16);
    rs += __shfl_xor(rs, 32);
    l_run = l_run * alpha + rs;

    // rescale O rows by their alpha (rows live at (lane>>4)*4+r; alpha lives at lane==row)
#pragma unroll
    for (int r = 0; r < 4; r++) {
      float ar = __shfl(alpha, (lane >> 4) * 4 + r);
#pragma unroll
      for (int fd = 0; fd < 4; fd++) o[fd][r] *= ar;
    }

    // write P[qrow][key] to wave-private LDS (swizzled)
#pragma unroll
    for (int kf = 0; kf < 4; kf++)
#pragma unroll
      for (int r = 0; r < 4; r++) {
        int key = kf * 16 + (lane >> 4) * 4 + r;
        int prow = lane & 15;
        int byteoff = (prow * 128 + key * 2) ^ ((prow & 7) << 4);
        *(short*)(PwB + byteoff) = (short)__bfloat16_as_short(__float2bfloat16(p[kf][r]));
      }
    asm volatile("s_waitcnt lgkmcnt(0)" ::: "memory");

    // O += P · V
#pragma unroll
    for (int ks = 0; ks < 2; ks++) {
      int prow = lane & 15;
      int pbyte = (prow * 128 + ks * 64 + (lane >> 4) * 16) ^ ((prow & 7) << 4);
      bf16x8 pa = *(const bf16x8*)(PwB + pbyte);
#pragma unroll
      for (int fd = 0; fd < 4; fd++) {
        int d = fd * 16 + (lane & 15);
        int vbyte = (d * 128 + ks * 64 + (lane >> 4) * 16) ^ ((d & 7) << 4);
        bf16x8 vf = *(const bf16x8*)(VtB + vbyte);
        mfma_bf16(o[fd], pa, vf);
      }
    }
    __syncthreads();
  }

  // epilogue: out[b][t][h*64+d]
  const int b = bh >> 4, h = bh & 15;
#pragma unroll
  for (int r = 0; r < 4; r++) {
    float lr = __shfl(l_run, (lane >> 4) * 4 + r);
    float inv = 1.0f / lr;
    int trow = q0 + wave * 16 + (lane >> 4) * 4 + r;
#pragma unroll
    for (int fd = 0; fd < 4; fd++) {
      int col = h * 64 + fd * 16 + (lane & 15);
      Ob[((size_t)(b * 2048 + trow)) * 1024 + col] = __float2bfloat16(o[fd][r] * inv);
    }
  }
}

extern "C" void kernel_launch(void* const* d_in, const int* in_sizes, int n_in,
                              void* d_out, int out_size, void* d_ws, size_t ws_size,
                              hipStream_t stream) {
  const float* x = (const float*)d_in[0];
  const float* w_qkv = (const float*)d_in[1];
  const float* w_out = (const float*)d_in[2];
  const float* b_out = (const float*)d_in[3];
  float* out = (float*)d_out;

  // workspace layout (bf16 elements): total 37748736 elems = 75.5 MB
  size_t need = (size_t)37748736 * 2;
  if (ws_size < need) return;  // failure signature: absmax == ref max (~0.27)
  __hip_bfloat16* wsp = (__hip_bfloat16*)d_ws;
  __hip_bfloat16* x_bf = wsp;                          // 8192*1024 (reused as attn out)
  __hip_bfloat16* wqkv_t = x_bf + 8192 * 1024;         // 3072*1024
  __hip_bfloat16* wout_t = wqkv_t + 3072 * 1024;       // 1024*1024
  __hip_bfloat16* qb = wout_t + 1024 * 1024;           // 8388608 each
  __hip_bfloat16* kb = qb + 8388608;
  __hip_bfloat16* vb = kb + 8388608;
  __hip_bfloat16* ab = x_bf;  // alias: x_bf dead after QKV GEMM

  cvt_f32_bf16<<<8192, 256, 0, stream>>>(x, x_bf, 8192 * 1024 / 4);
  transpose_cvt<<<dim3(3072 / 32, 1024 / 32), dim3(32, 8), 0, stream>>>(w_qkv, wqkv_t, 1024, 3072);
  transpose_cvt<<<dim3(1024 / 32, 1024 / 32), dim3(32, 8), 0, stream>>>(w_out, wout_t, 1024, 1024);
  gemm_bf16<0><<<dim3(24, 64), 256, 0, stream>>>(x_bf, wqkv_t, 8192, 3072, 1024,
                                                 qb, kb, vb, nullptr, nullptr);
  attn_fwd<<<dim3(32, 64), 256, 0, stream>>>(qb, kb, vb, ab);
  gemm_bf16<1><<<dim3(8, 64), 256, 0, stream>>>(ab, wout_t, 8192, 1024, 1024,
                                                nullptr, nullptr, nullptr, out, b_out);
}

// Round 2
// 247.442 us; speedup vs baseline: 1.4059x; 1.4059x over previous
//
#include <hip/hip_runtime.h>
#include <hip/hip_bf16.h>
#include <stdint.h>

// B=4, T=2048, INPUT_DIM=1024, DIM=64, H=16
typedef __attribute__((ext_vector_type(8))) short bf16x8;
typedef __attribute__((ext_vector_type(4))) short s16x4;
typedef __attribute__((ext_vector_type(4))) float f32x4;

__device__ __forceinline__ void mfma_bf16(f32x4& c, bf16x8 a, bf16x8 b) {
  asm("v_mfma_f32_16x16x32_bf16 %0, %1, %2, %0" : "+v"(c) : "v"(a), "v"(b));
}

__device__ __forceinline__ void gload_lds16(const void* g, void* lds) {
  __builtin_amdgcn_global_load_lds(
      (const __attribute__((address_space(1))) void*)g,
      (__attribute__((address_space(3))) void*)lds, 16, 0, 0);
}

// ---------------- f32 -> bf16 convert (vectorized) ----------------
__global__ void cvt_f32_bf16(const float* __restrict__ in, __hip_bfloat16* __restrict__ out, int n4) {
  int i = blockIdx.x * blockDim.x + threadIdx.x;
  if (i >= n4) return;
  float4 v = reinterpret_cast<const float4*>(in)[i];
  __hip_bfloat162 a = __float22bfloat162_rn(make_float2(v.x, v.y));
  __hip_bfloat162 b = __float22bfloat162_rn(make_float2(v.z, v.w));
  reinterpret_cast<__hip_bfloat162*>(out)[i * 2]     = a;
  reinterpret_cast<__hip_bfloat162*>(out)[i * 2 + 1] = b;
}

// ------------- transpose [R][C] f32 -> [C][R] bf16 -------------
__global__ void transpose_cvt(const float* __restrict__ in, __hip_bfloat16* __restrict__ out,
                              int R, int C) {
  __shared__ float tile[32][33];
  int c0 = blockIdx.x * 32, r0 = blockIdx.y * 32;
#pragma unroll
  for (int k = 0; k < 4; k++)
    tile[threadIdx.y + 8 * k][threadIdx.x] =
        in[(size_t)(r0 + threadIdx.y + 8 * k) * C + c0 + threadIdx.x];
  __syncthreads();
#pragma unroll
  for (int k = 0; k < 4; k++)
    out[(size_t)(c0 + threadIdx.y + 8 * k) * R + r0 + threadIdx.x] =
        __float2bfloat16(tile[threadIdx.x][threadIdx.y + 8 * k]);
}

// ---------------- bf16 GEMM, m97 structure: 128x128 tile, BK=32 ----------------
// A: [M][K] row-major bf16 ; Bt: [N][K] row-major bf16
// MODE 0: scatter Q (scaled 0.125) / K into [B,H,T,64]   (n-cols 0..2047)
// MODE 1: f32 out + bias
// MODE 2: V-tiles (n-cols 2048..3071): swapped mfma -> C^T, scatter Vt [bh][d][t]
template <int MODE>
__global__ __launch_bounds__(256) void gemm_bf16(
    const __hip_bfloat16* __restrict__ A, const __hip_bfloat16* __restrict__ Bt,
    int M, int N, int K,
    __hip_bfloat16* __restrict__ qb, __hip_bfloat16* __restrict__ kb,
    __hip_bfloat16* __restrict__ vt,
    float* __restrict__ outp, const float* __restrict__ bias) {
  constexpr int BK = 32;
  __shared__ __align__(16) __hip_bfloat16 As[128 * BK];
  __shared__ __align__(16) __hip_bfloat16 Bs[128 * BK];
  const int tid = threadIdx.x;
  const int wave = tid >> 6, lane = tid & 63;
  const int wr = wave >> 1, wc = wave & 1;
  const int m0 = blockIdx.y * 128;
  const int n0 = (MODE == 2 ? 2048 : 0) + blockIdx.x * 128;

  f32x4 acc[4][4];
#pragma unroll
  for (int i = 0; i < 4; i++)
#pragma unroll
    for (int j = 0; j < 4; j++) acc[i][j] = (f32x4)(0.0f);

  const int c0 = wave * 2, c1 = c0 + 1;
  const int srow0 = c0 * 16 + (lane >> 2);
  const int srow1 = c1 * 16 + (lane >> 2);
  const int scol = (lane & 3) * 8;
  const __hip_bfloat16* Ag0 = A + (size_t)(m0 + srow0) * K + scol;
  const __hip_bfloat16* Ag1 = A + (size_t)(m0 + srow1) * K + scol;
  const __hip_bfloat16* Bg0 = Bt + (size_t)(n0 + srow0) * K + scol;
  const __hip_bfloat16* Bg1 = Bt + (size_t)(n0 + srow1) * K + scol;
  __hip_bfloat16* AsP0 = &As[c0 * 512];
  __hip_bfloat16* AsP1 = &As[c1 * 512];
  __hip_bfloat16* BsP0 = &Bs[c0 * 512];
  __hip_bfloat16* BsP1 = &Bs[c1 * 512];

  for (int kk = 0; kk < K; kk += BK) {
    gload_lds16(Ag0 + kk, AsP0);
    gload_lds16(Ag1 + kk, AsP1);
    gload_lds16(Bg0 + kk, BsP0);
    gload_lds16(Bg1 + kk, BsP1);
    __syncthreads();
    bf16x8 af[4], bfr[4];
#pragma unroll
    for (int i = 0; i < 4; i++)
      af[i] = *(const bf16x8*)&As[(wr * 64 + i * 16 + (lane & 15)) * BK + (lane >> 4) * 8];
#pragma unroll
    for (int j = 0; j < 4; j++)
      bfr[j] = *(const bf16x8*)&Bs[(wc * 64 + j * 16 + (lane & 15)) * BK + (lane >> 4) * 8];
#pragma unroll
    for (int i = 0; i < 4; i++)
#pragma unroll
      for (int j = 0; j < 4; j++) {
        if constexpr (MODE == 2)
          mfma_bf16(acc[i][j], bfr[j], af[i]);  // D = C^T fragment
        else
          mfma_bf16(acc[i][j], af[i], bfr[j]);
      }
    __syncthreads();
  }

  if constexpr (MODE == 0) {
#pragma unroll
    for (int j = 0; j < 4; j++) {
      int col = n0 + wc * 64 + j * 16 + (lane & 15);  // col = sel*1024 + h*64 + d
      int sel = col >> 10;                            // 0=Q, 1=K
      int h = (col >> 6) & 15;
      int d = col & 63;
      __hip_bfloat16* dst = sel ? kb : qb;
      float scl = sel ? 1.0f : 0.125f;
#pragma unroll
      for (int i = 0; i < 4; i++) {
#pragma unroll
        for (int r = 0; r < 4; r++) {
          int row = m0 + wr * 64 + i * 16 + (lane >> 4) * 4 + r;  // b*2048 + t
          int b = row >> 11, t = row & 2047;
          dst[(((size_t)b * 16 + h) * 2048 + t) * 64 + d] = __float2bfloat16(acc[i][j][r] * scl);
        }
      }
    }
  } else if constexpr (MODE == 2) {
    // acc[i][j]: col(lane&15) = m-index (t), row(reg) = n-index (head/d)
#pragma unroll
    for (int j = 0; j < 4; j++) {
#pragma unroll
      for (int r = 0; r < 4; r++) {
        int nrow = n0 + wc * 64 + j * 16 + (lane >> 4) * 4 + r;  // 2048 + h*64 + d
        int h = (nrow >> 6) & 15;
        int d = nrow & 63;
#pragma unroll
        for (int i = 0; i < 4; i++) {
          int tcol = m0 + wr * 64 + i * 16 + (lane & 15);  // b*2048 + t
          int b = tcol >> 11, t = tcol & 2047;
          vt[(((size_t)b * 16 + h) * 64 + d) * 2048 + t] = __float2bfloat16(acc[i][j][r]);
        }
      }
    }
  } else {
#pragma unroll
    for (int j = 0; j < 4; j++) {
      int col = n0 + wc * 64 + j * 16 + (lane & 15);
      float bv = bias[col];
#pragma unroll
      for (int i = 0; i < 4; i++) {
#pragma unroll
        for (int r = 0; r < 4; r++) {
          int row = m0 + wr * 64 + i * 16 + (lane >> 4) * 4 + r;
          outp[(size_t)row * N + col] = acc[i][j][r] + bv;
        }
      }
    }
  }
}

// ---------------- flash attention ----------------
// Q,K: [bh][t][64] bf16 (Q pre-scaled by 0.125). Vt: [bh][d][2048] bf16.
// Out: [b*T + t][1024] bf16. 4 waves, 64 q-rows/block (16/wave), KV tiles of 64.
// Swapped QK^T: S^T = K·Q^T so each lane owns q-row (lane&15).
// K and Vt both staged via global_load_lds with pre-swizzled SOURCE addresses;
// double-buffered, counted vmcnt(4) prefetch (raw s_barrier, no full drain).
__global__ __launch_bounds__(256) void attn_fwd(
    const __hip_bfloat16* __restrict__ Qb, const __hip_bfloat16* __restrict__ Kb,
    const __hip_bfloat16* __restrict__ Vtg, __hip_bfloat16* __restrict__ Ob) {
  constexpr int T = 2048;
  __shared__ __align__(16) __hip_bfloat16 Ks[2][4096];     // [key][d] image, swizzled
  __shared__ __align__(16) __hip_bfloat16 Vs[2][4096];     // [d][key] image, swizzled
  __shared__ __align__(16) __hip_bfloat16 Ps[4][1024];     // per-wave P[qrow][key], swizzled
  const int tid = threadIdx.x, wave = tid >> 6, lane = tid & 63;

  // XCD-aware swizzle: 2048 blocks, XCD x gets bh 8x..8x+7 (K/V L2 locality)
  int id = ((int)blockIdx.x & 7) * 256 + ((int)blockIdx.x >> 3);
  const int bh = id >> 5, q0 = (id & 31) * 64;
  const size_t baseQ = (size_t)bh * T * 64;
  const size_t baseV = (size_t)bh * 64 * T;

  bf16x8 qf[2];
  {
    const int qrow = q0 + wave * 16 + (lane & 15);
#pragma unroll
    for (int ks = 0; ks < 2; ks++)
      qf[ks] = *(const bf16x8*)&Qb[baseQ + (size_t)qrow * 64 + ks * 32 + (lane >> 4) * 8];
  }

  float m_run = -3.0e38f, l_run = 0.0f;
  f32x4 o[4];
#pragma unroll
  for (int fd = 0; fd < 4; fd++) o[fd] = (f32x4)(0.0f);

  const int sr = lane >> 3;            // 0..7
  const int q8 = (lane & 7) ^ sr;      // swizzled 16B-chunk index within row
  const char* KgB = (const char*)(Kb + baseQ);
  const char* VgB = (const char*)(Vtg + baseV);
  const int cc0 = wave * 2, cc1 = cc0 + 1;
  char* PwB = (char*)&Ps[wave][0];
  const int prow = lane & 15, hi = lane >> 4;

#define STAGE(kt, buf)                                                                   \
  do {                                                                                   \
    char* kd = (char*)Ks[buf];                                                           \
    char* vd = (char*)Vs[buf];                                                           \
    gload_lds16(KgB + (size_t)((kt) * 64 + cc0 * 8 + sr) * 128 + q8 * 16, kd + cc0 * 1024); \
    gload_lds16(KgB + (size_t)((kt) * 64 + cc1 * 8 + sr) * 128 + q8 * 16, kd + cc1 * 1024); \
    gload_lds16(VgB + (size_t)(cc0 * 8 + sr) * 4096 + (kt) * 128 + q8 * 16, vd + cc0 * 1024); \
    gload_lds16(VgB + (size_t)(cc1 * 8 + sr) * 4096 + (kt) * 128 + q8 * 16, vd + cc1 * 1024); \
  } while (0)

  STAGE(0, 0);
  int cur = 0;

  for (int kt = 0; kt < T / 64; kt++) {
    if (kt < T / 64 - 1) {
      STAGE(kt + 1, cur ^ 1);
      asm volatile("s_waitcnt vmcnt(4)" ::: "memory");  // cur tile landed; 4 prefetch in flight
    } else {
      asm volatile("s_waitcnt vmcnt(0)" ::: "memory");
    }
    __builtin_amdgcn_s_barrier();
    __builtin_amdgcn_sched_barrier(0);
    const char* KsB = (const char*)Ks[cur];
    const char* VtB = (const char*)Vs[cur];

    // S^T = K · Q^T : lane owns (key = kf*16 + hi*4 + r, qrow = lane&15)
    f32x4 s[4];
#pragma unroll
    for (int kf = 0; kf < 4; kf++) s[kf] = (f32x4)(0.0f);
#pragma unroll
    for (int ks = 0; ks < 2; ks++) {
#pragma unroll
      for (int kf = 0; kf < 4; kf++) {
        int key = kf * 16 + prow;
        int byteoff = (key * 128 + ks * 64 + hi * 16) ^ ((key & 7) << 4);
        bf16x8 kfrag = *(const bf16x8*)(KsB + byteoff);
        mfma_bf16(s[kf], kfrag, qf[ks]);
      }
    }

    // online softmax (row = lane&15 local; reduce 16 in-reg + 2 shfl)
    float tm = s[0][0];
#pragma unroll
    for (int kf = 0; kf < 4; kf++)
#pragma unroll
      for (int r = 0; r < 4; r++) tm = fmaxf(tm, s[kf][r]);
    tm = fmaxf(tm, __shfl_xor(tm, 16));
    tm = fmaxf(tm, __shfl_xor(tm, 32));
    float mn = fmaxf(m_run, tm);
    float alpha = __expf(m_run - mn);
    m_run = mn;
    float rs = 0.0f;
    float p[4][4];
#pragma unroll
    for (int kf = 0; kf < 4; kf++)
#pragma unroll
      for (int r = 0; r < 4; r++) {
        float pv = __expf(s[kf][r] - mn);
        p[kf][r] = pv;
        rs += pv;
      }
    rs += __shfl_xor(rs, 16);
    rs += __shfl_xor(rs, 32);
    l_run = l_run * alpha + rs;

    // rescale O rows (row index (lane>>4)*4+r holds alpha at lane == row)
#pragma unroll
    for (int r = 0; r < 4; r++) {
      float ar = __shfl(alpha, hi * 4 + r);
#pragma unroll
      for (int fd = 0; fd < 4; fd++) o[fd][r] *= ar;
    }

    // P[qrow][key] -> wave-private LDS, vectorized b64 (4 keys/write), swizzled
#pragma unroll
    for (int kf = 0; kf < 4; kf++) {
      s16x4 pk;
      pk.x = (short)__bfloat16_as_short(__float2bfloat16(p[kf][0]));
      pk.y = (short)__bfloat16_as_short(__float2bfloat16(p[kf][1]));
      pk.z = (short)__bfloat16_as_short(__float2bfloat16(p[kf][2]));
      pk.w = (short)__bfloat16_as_short(__float2bfloat16(p[kf][3]));
      int wb = (prow * 128 + kf * 32 + hi * 8) ^ ((prow & 7) << 4);
      *(s16x4*)(PwB + wb) = pk;
    }

    // O += P · V
#pragma unroll
    for (int ks = 0; ks < 2; ks++) {
      int pbyte = (prow * 128 + ks * 64 + hi * 16) ^ ((prow & 7) << 4);
      bf16x8 pa = *(const bf16x8*)(PwB + pbyte);
#pragma unroll
      for (int fd = 0; fd < 4; fd++) {
        int d = fd * 16 + prow;
        int vbyte = (d * 128 + ks * 64 + hi * 16) ^ ((d & 7) << 4);
        bf16x8 vf = *(const bf16x8*)(VtB + vbyte);
        mfma_bf16(o[fd], pa, vf);
      }
    }
    __builtin_amdgcn_sched_barrier(0);
    __builtin_amdgcn_s_barrier();
    cur ^= 1;
  }
#undef STAGE

  // epilogue: out[b][t][h*64+d]
  const int b = bh >> 4, h = bh & 15;
#pragma unroll
  for (int r = 0; r < 4; r++) {
    float lr = __shfl(l_run, hi * 4 + r);
    float inv = 1.0f / lr;
    int trow = q0 + wave * 16 + hi * 4 + r;
#pragma unroll
    for (int fd = 0; fd < 4; fd++) {
      int col = h * 64 + fd * 16 + prow;
      Ob[((size_t)(b * 2048 + trow)) * 1024 + col] = __float2bfloat16(o[fd][r] * inv);
    }
  }
}

extern "C" void kernel_launch(void* const* d_in, const int* in_sizes, int n_in,
                              void* d_out, int out_size, void* d_ws, size_t ws_size,
                              hipStream_t stream) {
  const float* x = (const float*)d_in[0];
  const float* w_qkv = (const float*)d_in[1];
  const float* w_out = (const float*)d_in[2];
  const float* b_out = (const float*)d_in[3];
  float* out = (float*)d_out;

  size_t need = (size_t)37748736 * 2;
  if (ws_size < need) return;
  __hip_bfloat16* wsp = (__hip_bfloat16*)d_ws;
  __hip_bfloat16* x_bf = wsp;                          // 8192*1024 (reused as attn out)
  __hip_bfloat16* wqkv_t = x_bf + 8192 * 1024;         // 3072*1024
  __hip_bfloat16* wout_t = wqkv_t + 3072 * 1024;       // 1024*1024
  __hip_bfloat16* qb = wout_t + 1024 * 1024;           // [bh][t][64]
  __hip_bfloat16* kb = qb + 8388608;                   // [bh][t][64]
  __hip_bfloat16* vt = kb + 8388608;                   // [bh][d][2048]
  __hip_bfloat16* ab = x_bf;

  cvt_f32_bf16<<<8192, 256, 0, stream>>>(x, x_bf, 8192 * 1024 / 4);
  transpose_cvt<<<dim3(3072 / 32, 1024 / 32), dim3(32, 8), 0, stream>>>(w_qkv, wqkv_t, 1024, 3072);
  transpose_cvt<<<dim3(1024 / 32, 1024 / 32), dim3(32, 8), 0, stream>>>(w_out, wout_t, 1024, 1024);
  gemm_bf16<0><<<dim3(16, 64), 256, 0, stream>>>(x_bf, wqkv_t, 8192, 3072, 1024,
                                                 qb, kb, nullptr, nullptr, nullptr);
  gemm_bf16<2><<<dim3(8, 64), 256, 0, stream>>>(x_bf, wqkv_t, 8192, 3072, 1024,
                                                nullptr, nullptr, vt, nullptr, nullptr);
  attn_fwd<<<2048, 256, 0, stream>>>(qb, kb, vt, ab);
  gemm_bf16<1><<<dim3(8, 64), 256, 0, stream>>>(ab, wout_t, 8192, 1024, 1024,
                                                nullptr, nullptr, nullptr, out, b_out);
}